// Round 1
// baseline (2649.600 us; speedup 1.0000x reference)
//
#include <hip/hip_runtime.h>
#include <cstdint>
#include <cstddef>

#define HH 128   // hidden
#define II 64    // input
#define OO 64    // output
#define G3 384   // 3*H
#define BB 64    // batch
#define TT 2048  // time
#define GX_ROWS 32

__device__ __forceinline__ float sigf(float x) { return 1.0f / (1.0f + __expf(-x)); }
__device__ __forceinline__ float tanh_fast(float x) {
    x = fminf(20.0f, fmaxf(-20.0f, x));
    float e = __expf(2.0f * x);
    return (e - 1.0f) / (e + 1.0f);
}

// ---------------- gx = x @ W_ih^T + b_ih  (parallel GEMM) ----------------
// grid: BB*TT/GX_ROWS blocks, 384 threads. Thread g owns W_ih row g in regs.
__global__ __launch_bounds__(384) void gru_gx_kernel(
        const float* __restrict__ x, const float* __restrict__ W_ih,
        const float* __restrict__ b_ih, float* __restrict__ gx) {
    __shared__ __align__(16) float sx[GX_ROWS][II];
    const int g = threadIdx.x;
    const int64_t row0 = (int64_t)blockIdx.x * GX_ROWS;

    float w[II];
#pragma unroll
    for (int k = 0; k < II; ++k) w[k] = W_ih[g * II + k];
    const float bias = b_ih[g];

    for (int i = g; i < GX_ROWS * II; i += 384)
        ((float*)sx)[i] = x[row0 * II + i];
    __syncthreads();

    const float4* sx4 = (const float4*)sx;
#pragma unroll 4
    for (int r = 0; r < GX_ROWS; ++r) {
        float acc = bias;
#pragma unroll
        for (int k4 = 0; k4 < II / 4; ++k4) {
            float4 v = sx4[r * (II / 4) + k4];
            acc += w[4*k4+0]*v.x + w[4*k4+1]*v.y + w[4*k4+2]*v.z + w[4*k4+3]*v.w;
        }
        gx[(row0 + r) * (int64_t)G3 + g] = acc;
    }
}

// ---------------- recurrent scan: one block per batch, 384 threads -------
// HAS_GX: gx precomputed in ws, writes hs to ws (out-proj done later).
// !HAS_GX: fully fused (computes gx in-loop, out-proj in-loop).
template <bool HAS_GX>
__global__ __launch_bounds__(384, 2) void gru_scan_kernel(
        const float* __restrict__ x, const float* __restrict__ W_ih,
        const float* __restrict__ b_ih, const float* __restrict__ W_hh,
        const float* __restrict__ b_hh, const float* __restrict__ gx,
        float* __restrict__ hs, const float* __restrict__ W_out,
        const float* __restrict__ b_out, float* __restrict__ out) {
    __shared__ __align__(16) float sh[HH];
    __shared__ float sC[G3];
    __shared__ float sA[G3];
    __shared__ __align__(16) float sx[II];
    __shared__ __align__(16) float sWq[HH / 4][OO][4];  // W_out as [k4][o][4]
    __shared__ float sPart[4][OO];

    const int b = blockIdx.x;
    const int g = threadIdx.x;

    // W_hh row g -> registers (128 VGPRs)
    float whh[HH];
#pragma unroll
    for (int k = 0; k < HH; ++k) whh[k] = W_hh[g * HH + k];
    const float bh = b_hh[g];

    float wih[II];
    float bi = 0.0f;
    float bo = 0.0f;
    if constexpr (!HAS_GX) {
#pragma unroll
        for (int k = 0; k < II; ++k) wih[k] = W_ih[g * II + k];
        bi = b_ih[g];
        if (g < OO) bo = b_out[g];
        for (int i = g; i < OO * HH; i += 384) {
            int o = i / HH, k = i % HH;
            sWq[k >> 2][o][k & 3] = W_out[i];
        }
    }
    if (g < HH) sh[g] = 0.0f;
    __syncthreads();

    const float4* sh4 = (const float4*)sh;

    if constexpr (HAS_GX) {
        const float* gxb = gx + (size_t)b * TT * G3;
        float* hsb = hs + (size_t)b * TT * HH;
        float g0 = 0, g1 = 0, g2 = 0;
        if (g < HH) { g0 = gxb[g]; g1 = gxb[HH + g]; g2 = gxb[2 * HH + g]; }
        for (int t = 0; t < TT; ++t) {
            // prefetch next step's gx (hides HBM/L3 latency under the matvec)
            float n0 = 0, n1 = 0, n2 = 0;
            if (g < HH && t + 1 < TT) {
                const float* p = gxb + (size_t)(t + 1) * G3;
                n0 = p[g]; n1 = p[HH + g]; n2 = p[2 * HH + g];
            }
            float c = bh;
#pragma unroll
            for (int k4 = 0; k4 < HH / 4; ++k4) {
                float4 v = sh4[k4];
                c += whh[4*k4+0]*v.x + whh[4*k4+1]*v.y + whh[4*k4+2]*v.z + whh[4*k4+3]*v.w;
            }
            sC[g] = c;
            __syncthreads();  // B1: sC ready, all sh reads done
            if (g < HH) {
                float r = sigf(g0 + sC[g]);
                float z = sigf(g1 + sC[HH + g]);
                float n = tanh_fast(g2 + r * sC[2 * HH + g]);
                float hn = (1.0f - z) * n + z * sh[g];
                sh[g] = hn;
                hsb[(size_t)t * HH + g] = hn;
                g0 = n0; g1 = n1; g2 = n2;
            }
            __syncthreads();  // B2: sh updated before next matvec
        }
    } else {
        const float* xb = x + (size_t)b * TT * II;
        float* outb = out + (size_t)b * TT * OO;
        const float4* sx4 = (const float4*)sx;
        for (int t = 0; t < TT; ++t) {
            if (g < II) sx[g] = xb[(size_t)t * II + g];
            __syncthreads();  // B1: sx ready
            float a = bi, c = bh;
#pragma unroll
            for (int k4 = 0; k4 < II / 4; ++k4) {
                float4 v = sx4[k4];
                a += wih[4*k4+0]*v.x + wih[4*k4+1]*v.y + wih[4*k4+2]*v.z + wih[4*k4+3]*v.w;
            }
#pragma unroll
            for (int k4 = 0; k4 < HH / 4; ++k4) {
                float4 v = sh4[k4];
                c += whh[4*k4+0]*v.x + whh[4*k4+1]*v.y + whh[4*k4+2]*v.z + whh[4*k4+3]*v.w;
            }
            sA[g] = a; sC[g] = c;
            __syncthreads();  // B2: gate inputs ready
            if (g < HH) {
                float r = sigf(sA[g] + sC[g]);
                float z = sigf(sA[HH + g] + sC[HH + g]);
                float n = tanh_fast(sA[2 * HH + g] + r * sC[2 * HH + g]);
                sh[g] = (1.0f - z) * n + z * sh[g];
            }
            __syncthreads();  // B3: h updated
            if (g < 256) {
                const int o = g & 63, part = g >> 6;
                float s = 0.0f;
#pragma unroll
                for (int k4 = 0; k4 < 8; ++k4) {
                    const float4 wv = *(const float4*)sWq[part * 8 + k4][o];
                    const float4 hv = sh4[part * 8 + k4];
                    s += wv.x*hv.x + wv.y*hv.y + wv.z*hv.z + wv.w*hv.w;
                }
                sPart[part][o] = s;
            }
            __syncthreads();  // B4: partials ready
            if (g < OO)
                outb[(size_t)t * OO + g] =
                    bo + sPart[0][g] + sPart[1][g] + sPart[2][g] + sPart[3][g];
        }
    }
}

// ---------------- out = hs @ W_out^T + b_out (parallel GEMM) -------------
// one thread per row; 64 f32 accumulators/thread; W_out broadcast from LDS.
__global__ __launch_bounds__(256) void gru_outproj_kernel(
        const float* __restrict__ hs, const float* __restrict__ W_out,
        const float* __restrict__ b_out, float* __restrict__ out) {
    __shared__ __align__(16) float sW[HH / 4][OO][4];
    __shared__ float sb[OO];
    const int tid = threadIdx.x;
    for (int i = tid; i < OO * HH; i += 256) {
        int o = i / HH, k = i % HH;
        sW[k >> 2][o][k & 3] = W_out[i];
    }
    if (tid < OO) sb[tid] = b_out[tid];
    __syncthreads();

    const int64_t row = (int64_t)blockIdx.x * 256 + tid;
    const float4* hrow = (const float4*)(hs + row * HH);
    float acc[OO];
#pragma unroll
    for (int o = 0; o < OO; ++o) acc[o] = 0.0f;
    for (int k4 = 0; k4 < HH / 4; ++k4) {
        float4 h4 = hrow[k4];
#pragma unroll
        for (int o = 0; o < OO; ++o) {
            const float4 w = *(const float4*)sW[k4][o];
            acc[o] += w.x*h4.x + w.y*h4.y + w.z*h4.z + w.w*h4.w;
        }
    }
    float* orow = out + row * OO;
#pragma unroll
    for (int o = 0; o < OO; ++o) orow[o] = sb[o] + acc[o];
}

extern "C" void kernel_launch(void* const* d_in, const int* in_sizes, int n_in,
                              void* d_out, int out_size, void* d_ws, size_t ws_size,
                              hipStream_t stream) {
    const float* x     = (const float*)d_in[0];
    const float* W_ih  = (const float*)d_in[1];
    const float* W_hh  = (const float*)d_in[2];
    const float* b_ih  = (const float*)d_in[3];
    const float* b_hh  = (const float*)d_in[4];
    const float* W_out = (const float*)d_in[5];
    const float* b_out = (const float*)d_in[6];
    float* out = (float*)d_out;

    const size_t need_gx = (size_t)BB * TT * G3 * sizeof(float);  // 201,326,592
    const size_t need_hs = (size_t)BB * TT * HH * sizeof(float);  //  67,108,864

    if (ws_size >= need_gx + need_hs) {
        float* gx = (float*)d_ws;
        float* hs = (float*)((char*)d_ws + need_gx);
        gru_gx_kernel<<<(BB * TT) / GX_ROWS, 384, 0, stream>>>(x, W_ih, b_ih, gx);
        gru_scan_kernel<true><<<BB, 384, 0, stream>>>(
            x, W_ih, b_ih, W_hh, b_hh, gx, hs, W_out, b_out, out);
        gru_outproj_kernel<<<(BB * TT) / 256, 256, 0, stream>>>(hs, W_out, b_out, out);
    } else {
        gru_scan_kernel<false><<<BB, 384, 0, stream>>>(
            x, W_ih, b_ih, W_hh, b_hh, nullptr, nullptr, W_out, b_out, out);
    }
}